// Round 1
// baseline (37234.308 us; speedup 1.0000x reference)
//
#include <hip/hip_runtime.h>

constexpr int S_ = 128;
constexpr int NR = 34;      // P*J
constexpr int DR = 128;     // DRNN
constexpr int DH = 256;     // DHID
constexpr int G3 = 384;     // 3*DRNN
constexpr float DT_ = 0.1f;
constexpr int RPB = 4;      // rows per block (one wave each)
constexpr int NROWS = 32 * 34; // 1088

__device__ __forceinline__ float fast_tanh(float x) {
    float e = __expf(2.0f * x);
    return 1.0f - 2.0f / (e + 1.0f);
}
__device__ __forceinline__ float fast_sigmoid(float x) {
    return 1.0f / (1.0f + __expf(-x));
}
__device__ __forceinline__ void fma4(float4& a, float s, const float4 v) {
    a.x = fmaf(s, v.x, a.x); a.y = fmaf(s, v.y, a.y);
    a.z = fmaf(s, v.z, a.z); a.w = fmaf(s, v.w, a.w);
}
__device__ __forceinline__ void fma2(float2& a, float s, const float2 v) {
    a.x = fmaf(s, v.x, a.x); a.y = fmaf(s, v.y, a.y);
}

__global__ __launch_bounds__(256) void odernn_fp32(
    const float* __restrict__ x2d, const int* __restrict__ mask,
    const float* __restrict__ w0, const float* __restrict__ b0,
    const float* __restrict__ w1, const float* __restrict__ b1,
    const float* __restrict__ w2, const float* __restrict__ b2,
    const float* __restrict__ wih0, const float* __restrict__ whh0,
    const float* __restrict__ bih0, const float* __restrict__ bhh0,
    const float* __restrict__ wih1, const float* __restrict__ whh1,
    const float* __restrict__ bih1, const float* __restrict__ bhh1,
    const float* __restrict__ wout, const float* __restrict__ bout,
    const float* __restrict__ h0, float* __restrict__ out)
{
    __shared__ float sh[RPB][DR];    // current h / h1 (per-wave private)
    __shared__ float st1[RPB][DH];
    __shared__ float st2[RPB][DH];
    __shared__ float sh2[RPB][DR];

    const int tid = (int)threadIdx.x;
    const int w = tid >> 6;     // wave id = row slot in block
    const int t = tid & 63;     // lane
    const int grow = (int)blockIdx.x * RPB + w;
    const int b = grow / NR;
    const int n = grow - b * NR;

    const int c4 = 4 * t;   // column base for 256-wide layers
    const int c2 = 2 * t;   // column base for 128-wide layers

    // ---- preload biases / tiny weights into registers (reused all 128 steps) ----
    const float4 pb0 = *(const float4*)(b0 + c4);
    const float4 pb1 = *(const float4*)(b1 + c4);
    const float2 pb2 = *(const float2*)(b2 + c2);

    float2 pbih0[3], pbhh0[3], pbih1[3], pbhh1[3];
    float2 pwi0[2][3];
#pragma unroll
    for (int g = 0; g < 3; ++g) {
        pbih0[g] = *(const float2*)(bih0 + g * DR + c2);
        pbhh0[g] = *(const float2*)(bhh0 + g * DR + c2);
        pbih1[g] = *(const float2*)(bih1 + g * DR + c2);
        pbhh1[g] = *(const float2*)(bhh1 + g * DR + c2);
        pwi0[0][g] = *(const float2*)(wih0 + 0 * G3 + g * DR + c2);
        pwi0[1][g] = *(const float2*)(wih0 + 1 * G3 + g * DR + c2);
    }
    float pwo[2][3];
#pragma unroll
    for (int i = 0; i < 2; ++i)
#pragma unroll
        for (int d = 0; d < 3; ++d)
            pwo[i][d] = wout[(c2 + i) * 3 + d];
    const float pbo0 = bout[0], pbo1 = bout[1], pbo2 = bout[2];

    // ---- init hidden state (h0 broadcast to every row) ----
    {
        float2 hv = *(const float2*)(h0 + c2);
        *(float2*)&sh[w][c2] = hv;
    }
    __syncthreads();

    for (int s = 0; s < S_; ++s) {
        const int idx = (b * S_ + s) * NR + n;
        const float mm = (float)mask[idx];
        const float xm0 = x2d[2 * idx] * mm;
        const float xm1 = x2d[2 * idx + 1] * mm;

        // ---------------- 4 Euler steps of the ODE MLP ----------------
        for (int it = 0; it < 4; ++it) {
            // layer 1: sh(128) -> st1(256), tanh
            {
                float4 a = pb0;
                const float* wp = w0 + c4;
#pragma unroll 4
                for (int k4 = 0; k4 < DR; k4 += 4) {
                    const float4 hv = *(const float4*)&sh[w][k4];
                    fma4(a, hv.x, *(const float4*)(wp + (k4 + 0) * DH));
                    fma4(a, hv.y, *(const float4*)(wp + (k4 + 1) * DH));
                    fma4(a, hv.z, *(const float4*)(wp + (k4 + 2) * DH));
                    fma4(a, hv.w, *(const float4*)(wp + (k4 + 3) * DH));
                }
                float4 o;
                o.x = fast_tanh(a.x); o.y = fast_tanh(a.y);
                o.z = fast_tanh(a.z); o.w = fast_tanh(a.w);
                *(float4*)&st1[w][c4] = o;
            }
            __syncthreads();
            // layer 2: st1(256) -> st2(256), tanh
            {
                float4 a = pb1;
                const float* wp = w1 + c4;
#pragma unroll 4
                for (int k4 = 0; k4 < DH; k4 += 4) {
                    const float4 hv = *(const float4*)&st1[w][k4];
                    fma4(a, hv.x, *(const float4*)(wp + (k4 + 0) * DH));
                    fma4(a, hv.y, *(const float4*)(wp + (k4 + 1) * DH));
                    fma4(a, hv.z, *(const float4*)(wp + (k4 + 2) * DH));
                    fma4(a, hv.w, *(const float4*)(wp + (k4 + 3) * DH));
                }
                float4 o;
                o.x = fast_tanh(a.x); o.y = fast_tanh(a.y);
                o.z = fast_tanh(a.z); o.w = fast_tanh(a.w);
                *(float4*)&st2[w][c4] = o;
            }
            __syncthreads();
            // layer 3: st2(256) -> h update (128), linear; h1 = h + DT*(...)
            {
                float2 a2 = pb2;
                const float* wp = w2 + c2;
#pragma unroll 4
                for (int k4 = 0; k4 < DH; k4 += 4) {
                    const float4 hv = *(const float4*)&st2[w][k4];
                    fma2(a2, hv.x, *(const float2*)(wp + (k4 + 0) * DR));
                    fma2(a2, hv.y, *(const float2*)(wp + (k4 + 1) * DR));
                    fma2(a2, hv.z, *(const float2*)(wp + (k4 + 2) * DR));
                    fma2(a2, hv.w, *(const float2*)(wp + (k4 + 3) * DR));
                }
                float2 hcur = *(const float2*)&sh[w][c2];
                hcur.x = fmaf(DT_, a2.x, hcur.x);
                hcur.y = fmaf(DT_, a2.y, hcur.y);
                *(float2*)&sh[w][c2] = hcur;
            }
            __syncthreads();
        }

        // ---------------- y output: h1 @ wout + bout ----------------
        {
            const float2 h1v = *(const float2*)&sh[w][c2];
            float p0 = h1v.x * pwo[0][0] + h1v.y * pwo[1][0];
            float p1 = h1v.x * pwo[0][1] + h1v.y * pwo[1][1];
            float p2 = h1v.x * pwo[0][2] + h1v.y * pwo[1][2];
#pragma unroll
            for (int m = 32; m >= 1; m >>= 1) {
                p0 += __shfl_xor(p0, m, 64);
                p1 += __shfl_xor(p1, m, 64);
                p2 += __shfl_xor(p2, m, 64);
            }
            if (t == 0) {
                out[idx * 3 + 0] = p0 + pbo0;
                out[idx * 3 + 1] = p1 + pbo1;
                out[idx * 3 + 2] = p2 + pbo2;
            }
        }

        // ---------------- GRU cell 0: input = masked x, hidden = h1 ----------------
        {
            float2 ar = pbhh0[0], az = pbhh0[1], ag = pbhh0[2];
            const float* wh = whh0 + c2;
#pragma unroll 2
            for (int k4 = 0; k4 < DR; k4 += 4) {
                const float4 hv = *(const float4*)&sh[w][k4];
                const float hk[4] = {hv.x, hv.y, hv.z, hv.w};
#pragma unroll
                for (int j = 0; j < 4; ++j) {
                    const float* row = wh + (k4 + j) * G3;
                    fma2(ar, hk[j], *(const float2*)(row));
                    fma2(az, hk[j], *(const float2*)(row + DR));
                    fma2(ag, hk[j], *(const float2*)(row + 2 * DR));
                }
            }
            float2 gir, giz, gig;
            gir.x = pbih0[0].x + xm0 * pwi0[0][0].x + xm1 * pwi0[1][0].x;
            gir.y = pbih0[0].y + xm0 * pwi0[0][0].y + xm1 * pwi0[1][0].y;
            giz.x = pbih0[1].x + xm0 * pwi0[0][1].x + xm1 * pwi0[1][1].x;
            giz.y = pbih0[1].y + xm0 * pwi0[0][1].y + xm1 * pwi0[1][1].y;
            gig.x = pbih0[2].x + xm0 * pwi0[0][2].x + xm1 * pwi0[1][2].x;
            gig.y = pbih0[2].y + xm0 * pwi0[0][2].y + xm1 * pwi0[1][2].y;

            float2 rg, zg, ng;
            rg.x = fast_sigmoid(gir.x + ar.x); rg.y = fast_sigmoid(gir.y + ar.y);
            zg.x = fast_sigmoid(giz.x + az.x); zg.y = fast_sigmoid(giz.y + az.y);
            ng.x = fast_tanh(gig.x + rg.x * ag.x); ng.y = fast_tanh(gig.y + rg.y * ag.y);
            const float2 h1v = *(const float2*)&sh[w][c2];
            float2 h2v;
            h2v.x = (1.0f - zg.x) * ng.x + zg.x * h1v.x;
            h2v.y = (1.0f - zg.y) * ng.y + zg.y * h1v.y;
            *(float2*)&sh2[w][c2] = h2v;
        }
        __syncthreads();

        // ---------------- GRU cell 1: input = h2, hidden = h1 ----------------
        {
            float2 ir = pbih1[0], iz = pbih1[1], ig = pbih1[2];
            float2 hr = pbhh1[0], hz = pbhh1[1], hg = pbhh1[2];
            const float* wi = wih1 + c2;
            const float* wh = whh1 + c2;
#pragma unroll 2
            for (int k4 = 0; k4 < DR; k4 += 4) {
                const float4 av = *(const float4*)&sh2[w][k4];
                const float4 hv = *(const float4*)&sh[w][k4];
                const float ak[4] = {av.x, av.y, av.z, av.w};
                const float hk[4] = {hv.x, hv.y, hv.z, hv.w};
#pragma unroll
                for (int j = 0; j < 4; ++j) {
                    const float* ri = wi + (k4 + j) * G3;
                    const float* rh = wh + (k4 + j) * G3;
                    fma2(ir, ak[j], *(const float2*)(ri));
                    fma2(iz, ak[j], *(const float2*)(ri + DR));
                    fma2(ig, ak[j], *(const float2*)(ri + 2 * DR));
                    fma2(hr, hk[j], *(const float2*)(rh));
                    fma2(hz, hk[j], *(const float2*)(rh + DR));
                    fma2(hg, hk[j], *(const float2*)(rh + 2 * DR));
                }
            }
            float2 rg, zg, ng;
            rg.x = fast_sigmoid(ir.x + hr.x); rg.y = fast_sigmoid(ir.y + hr.y);
            zg.x = fast_sigmoid(iz.x + hz.x); zg.y = fast_sigmoid(iz.y + hz.y);
            ng.x = fast_tanh(ig.x + rg.x * hg.x); ng.y = fast_tanh(ig.y + rg.y * hg.y);
            const float2 h1v = *(const float2*)&sh[w][c2];
            float2 hb;
            hb.x = (1.0f - zg.x) * ng.x + zg.x * h1v.x;
            hb.y = (1.0f - zg.y) * ng.y + zg.y * h1v.y;
            float2 hn;
            hn.x = (mm != 0.0f) ? hb.x : h1v.x;
            hn.y = (mm != 0.0f) ? hb.y : h1v.y;
            *(float2*)&sh[w][c2] = hn;
        }
        __syncthreads();
    }
}

extern "C" void kernel_launch(void* const* d_in, const int* in_sizes, int n_in,
                              void* d_out, int out_size, void* d_ws, size_t ws_size,
                              hipStream_t stream) {
    const float* x2d  = (const float*)d_in[0];
    const int*   mask = (const int*)d_in[1];
    const float* w0   = (const float*)d_in[2];
    const float* b0   = (const float*)d_in[3];
    const float* w1   = (const float*)d_in[4];
    const float* b1   = (const float*)d_in[5];
    const float* w2   = (const float*)d_in[6];
    const float* b2   = (const float*)d_in[7];
    const float* wih0 = (const float*)d_in[8];
    const float* whh0 = (const float*)d_in[9];
    const float* bih0 = (const float*)d_in[10];
    const float* bhh0 = (const float*)d_in[11];
    const float* wih1 = (const float*)d_in[12];
    const float* whh1 = (const float*)d_in[13];
    const float* bih1 = (const float*)d_in[14];
    const float* bhh1 = (const float*)d_in[15];
    const float* wout = (const float*)d_in[16];
    const float* bout = (const float*)d_in[17];
    const float* h0   = (const float*)d_in[18];
    float* out = (float*)d_out;

    dim3 grid(NROWS / RPB);  // 272 blocks
    dim3 block(256);         // 4 waves, one row each
    hipLaunchKernelGGL(odernn_fp32, grid, block, 0, stream,
        x2d, mask, w0, b0, w1, b1, w2, b2,
        wih0, whh0, bih0, bhh0, wih1, whh1, bih1, bhh1,
        wout, bout, h0, out);
}

// Round 3
// 6896.267 us; speedup vs baseline: 5.3992x; 5.3992x over previous
//
#include <hip/hip_runtime.h>

typedef _Float16 f16x8 __attribute__((ext_vector_type(8)));
typedef float f32x4 __attribute__((ext_vector_type(4)));

constexpr int S_ = 128;
constexpr float DT_ = 0.1f;
constexpr float LS = 2048.0f;          // lo-term scale (2^11) keeps fp16 lo parts normal
constexpr float INV = 1.0f / 2048.0f;

#define MFMA(a, b, c) __builtin_amdgcn_mfma_f32_16x16x32_f16((a), (b), (c), 0, 0, 0)

// bias LDS offsets (floats)
#define OB0   0
#define OB1   256
#define OB2   512
#define OBHH0 640
#define OBIH0 1024
#define OBIH1 1408
#define OBHH1 1792
#define NBIAS 2176

__device__ __forceinline__ float fast_tanh(float x) {
    float e = __expf(2.0f * x);
    return 1.0f - 2.0f / (e + 1.0f);
}
__device__ __forceinline__ float fast_sigmoid(float x) {
    return 1.0f / (1.0f + __expf(-x));
}

// fp32 row-major KxN -> fp16 hi/lo MFMA-B-fragment blobs.
// Tile (nt,kt) at ((nt*KT)+kt)*512; elem lane*8+j <-> B[kt*32+(lane>>4)*8+j][nt*16+(lane&15)].
__global__ void prep_hl(const float* __restrict__ src, _Float16* __restrict__ hi,
                        _Float16* __restrict__ lo, int K, int N) {
    int e = blockIdx.x * 256 + threadIdx.x;
    if (e >= K * N) return;
    int tile = e >> 9, r = e & 511;
    int lane = r >> 3, j = r & 7;
    int KT = K >> 5;
    int nt = tile / KT, kt = tile - nt * KT;
    int k = kt * 32 + ((lane >> 4) << 3) + j;
    int n = nt * 16 + (lane & 15);
    float v = src[k * N + n];
    _Float16 h = (_Float16)v;
    hi[e] = h;
    lo[e] = (_Float16)((v - (float)h) * LS);
}

__global__ __launch_bounds__(512, 2) void odernn_mfma(
    const float* __restrict__ x2d, const int* __restrict__ maskp,
    const _Float16* __restrict__ w0h, const _Float16* __restrict__ w0l,
    const _Float16* __restrict__ w1hg, const _Float16* __restrict__ w1lg,
    const _Float16* __restrict__ w2h, const _Float16* __restrict__ w2l,
    const _Float16* __restrict__ hh0h, const _Float16* __restrict__ hh0l,
    const _Float16* __restrict__ ih1h, const _Float16* __restrict__ ih1l,
    const _Float16* __restrict__ hh1h, const _Float16* __restrict__ hh1l,
    const float* __restrict__ b0, const float* __restrict__ b1,
    const float* __restrict__ b2, const float* __restrict__ bhh0,
    const float* __restrict__ bih0, const float* __restrict__ wih0,
    const float* __restrict__ bih1, const float* __restrict__ bhh1,
    const float* __restrict__ wout, const float* __restrict__ bout,
    const float* __restrict__ h0, float* __restrict__ out)
{
    __shared__ float hF[16][128];                       // fp32 master hidden state
    __shared__ _Float16 bAh[16][264], bAl[16][264];     // t2 (256-wide) hi/lo
    __shared__ _Float16 bBh[16][264], bBl[16][264];     // t1 / h2 hi/lo
    __shared__ _Float16 bHh[16][136], bHl[16][136];     // current h / h1 hi/lo
    __shared__ float sbias[NBIAS];
    __shared__ float swi0[768];
    __shared__ float swout[384];
    __shared__ float sbout[4];
    __shared__ float sx0[16], sx1[16], smm[16];
    __shared__ int sIdx[16];

    const int tid = (int)threadIdx.x;
    const int wv = tid >> 6;            // wave 0..7
    const int l = tid & 63;
    const int lrow = l & 15;            // A-row / D-col within tile
    const int lk8 = (l >> 4) << 3;      // k-octet within 32-wide k-tile
    const int rbase = (l >> 4) << 2;    // D-row base for this lane

    // ---- LDS init ----
    for (int e = tid; e < 256; e += 512) { sbias[OB0 + e] = b0[e]; sbias[OB1 + e] = b1[e]; }
    for (int e = tid; e < 128; e += 512) sbias[OB2 + e] = b2[e];
    for (int e = tid; e < 384; e += 512) {
        sbias[OBHH0 + e] = bhh0[e];
        sbias[OBIH0 + e] = bih0[e];
        sbias[OBIH1 + e] = bih1[e];
        sbias[OBHH1 + e] = bhh1[e];
        swout[e] = wout[e];
    }
    for (int e = tid; e < 768; e += 512) swi0[e] = wih0[e];
    if (tid < 3) sbout[tid] = bout[tid];
    for (int e = tid; e < 2048; e += 512) hF[e >> 7][e & 127] = h0[e & 127];
    if (tid < 16) {
        int grow = (int)blockIdx.x * 16 + tid;
        int bb = grow / 34, nn = grow - bb * 34;
        sIdx[tid] = bb * (S_ * 34) + nn;
    }

    // ---- w1 (256x256) persistent in registers: this wave's 2 n-tiles ----
    f16x8 w1rh[2][8], w1rl[2][8];
#pragma unroll
    for (int t = 0; t < 2; ++t) {
        const _Float16* ph = w1hg + (size_t)((wv + 8 * t) * 8) * 512 + l * 8;
        const _Float16* pl = w1lg + (size_t)((wv + 8 * t) * 8) * 512 + l * 8;
#pragma unroll
        for (int kt = 0; kt < 8; ++kt) {
            w1rh[t][kt] = *(const f16x8*)(ph + kt * 512);
            w1rl[t][kt] = *(const f16x8*)(pl + kt * 512);
        }
    }
    __syncthreads();

    for (int s = 0; s < S_; ++s) {
        // ---- step top: x/mask load + cast hF -> bufH ----
        if (tid < 16) {
            int idx = sIdx[tid] + s * 34;
            float fm = (float)maskp[idx];
            smm[tid] = fm;
            sx0[tid] = x2d[2 * idx] * fm;
            sx1[tid] = x2d[2 * idx + 1] * fm;
        }
        for (int e = tid; e < 2048; e += 512) {
            int row = e >> 7, col = e & 127;
            float v = hF[row][col];
            _Float16 hh = (_Float16)v;
            bHh[row][col] = hh;
            bHl[row][col] = (_Float16)((v - (float)hh) * LS);
        }
        __syncthreads();

        // ================= 4 Euler steps =================
        for (int it = 0; it < 4; ++it) {
            // P1: t1 = tanh(h @ w0 + b0) -> bufB   (K=128 KT=4, NT=16: 2/wave)
            {
                const int n0 = wv << 4, n1 = (wv + 8) << 4;
                float bv0 = sbias[OB0 + n0 + lrow], bv1 = sbias[OB0 + n1 + lrow];
                f32x4 a0 = {bv0, bv0, bv0, bv0}, a1 = {bv1, bv1, bv1, bv1};
                f32x4 e0 = {0, 0, 0, 0}, e1 = {0, 0, 0, 0};
                const f16x8* B0h = (const f16x8*)(w0h + (size_t)(wv * 4) * 512) + l;
                const f16x8* B0l = (const f16x8*)(w0l + (size_t)(wv * 4) * 512) + l;
                const f16x8* B1h = (const f16x8*)(w0h + (size_t)((wv + 8) * 4) * 512) + l;
                const f16x8* B1l = (const f16x8*)(w0l + (size_t)((wv + 8) * 4) * 512) + l;
#pragma unroll
                for (int kt = 0; kt < 4; ++kt) {
                    f16x8 ah = *(const f16x8*)&bHh[lrow][kt * 32 + lk8];
                    f16x8 al = *(const f16x8*)&bHl[lrow][kt * 32 + lk8];
                    f16x8 bh0 = B0h[kt * 64], bl0 = B0l[kt * 64];
                    f16x8 bh1 = B1h[kt * 64], bl1 = B1l[kt * 64];
                    a0 = MFMA(ah, bh0, a0);
                    e0 = MFMA(ah, bl0, e0);
                    e0 = MFMA(al, bh0, e0);
                    a1 = MFMA(ah, bh1, a1);
                    e1 = MFMA(ah, bl1, e1);
                    e1 = MFMA(al, bh1, e1);
                }
#pragma unroll
                for (int r = 0; r < 4; ++r) {
                    int row = rbase + r;
                    float v0 = fast_tanh(a0[r] + e0[r] * INV);
                    float v1 = fast_tanh(a1[r] + e1[r] * INV);
                    _Float16 hh = (_Float16)v0;
                    bBh[row][n0 + lrow] = hh;
                    bBl[row][n0 + lrow] = (_Float16)((v0 - (float)hh) * LS);
                    hh = (_Float16)v1;
                    bBh[row][n1 + lrow] = hh;
                    bBl[row][n1 + lrow] = (_Float16)((v1 - (float)hh) * LS);
                }
            }
            __syncthreads();

            // P2: t2 = tanh(t1 @ w1 + b1) -> bufA  (K=256 KT=8; w1 in registers)
            {
                const int n0 = wv << 4, n1 = (wv + 8) << 4;
                float bv0 = sbias[OB1 + n0 + lrow], bv1 = sbias[OB1 + n1 + lrow];
                f32x4 a0 = {bv0, bv0, bv0, bv0}, a1 = {bv1, bv1, bv1, bv1};
                f32x4 e0 = {0, 0, 0, 0}, e1 = {0, 0, 0, 0};
#pragma unroll
                for (int kt = 0; kt < 8; ++kt) {
                    f16x8 ah = *(const f16x8*)&bBh[lrow][kt * 32 + lk8];
                    f16x8 al = *(const f16x8*)&bBl[lrow][kt * 32 + lk8];
                    a0 = MFMA(ah, w1rh[0][kt], a0);
                    e0 = MFMA(ah, w1rl[0][kt], e0);
                    e0 = MFMA(al, w1rh[0][kt], e0);
                    a1 = MFMA(ah, w1rh[1][kt], a1);
                    e1 = MFMA(ah, w1rl[1][kt], e1);
                    e1 = MFMA(al, w1rh[1][kt], e1);
                }
#pragma unroll
                for (int r = 0; r < 4; ++r) {
                    int row = rbase + r;
                    float v0 = fast_tanh(a0[r] + e0[r] * INV);
                    float v1 = fast_tanh(a1[r] + e1[r] * INV);
                    _Float16 hh = (_Float16)v0;
                    bAh[row][n0 + lrow] = hh;
                    bAl[row][n0 + lrow] = (_Float16)((v0 - (float)hh) * LS);
                    hh = (_Float16)v1;
                    bAh[row][n1 + lrow] = hh;
                    bAl[row][n1 + lrow] = (_Float16)((v1 - (float)hh) * LS);
                }
            }
            __syncthreads();

            // P3: f = t2 @ w2 + b2 ; hF += DT*f ; cast new h -> bufH  (K=256 KT=8, NT=8)
            {
                const int n0 = wv << 4;
                float bv = sbias[OB2 + n0 + lrow];
                f32x4 acc = {bv, bv, bv, bv};
                f32x4 ecc = {0, 0, 0, 0};
                const f16x8* Bh = (const f16x8*)(w2h + (size_t)(wv * 8) * 512) + l;
                const f16x8* Bl = (const f16x8*)(w2l + (size_t)(wv * 8) * 512) + l;
#pragma unroll
                for (int kt = 0; kt < 8; ++kt) {
                    f16x8 ah = *(const f16x8*)&bAh[lrow][kt * 32 + lk8];
                    f16x8 al = *(const f16x8*)&bAl[lrow][kt * 32 + lk8];
                    f16x8 bh = Bh[kt * 64], bl = Bl[kt * 64];
                    acc = MFMA(ah, bh, acc);
                    ecc = MFMA(ah, bl, ecc);
                    ecc = MFMA(al, bh, ecc);
                }
#pragma unroll
                for (int r = 0; r < 4; ++r) {
                    int row = rbase + r, col = n0 + lrow;
                    float v = hF[row][col] + DT_ * (acc[r] + ecc[r] * INV);
                    hF[row][col] = v;
                    _Float16 hh = (_Float16)v;
                    bHh[row][col] = hh;
                    bHl[row][col] = (_Float16)((v - (float)hh) * LS);
                }
            }
            __syncthreads();
        }

        // P5: gh0 = h1 @ whh0 + bhh0 (KT=4, NT=24: 3/wave) ; y-out ; GRU0 combine -> bufB
        {
            f32x4 acc0, acc1, acc2, ecc0, ecc1, ecc2;
            {
                float v0 = sbias[OBHH0 + ((wv) << 4) + lrow];
                float v1 = sbias[OBHH0 + ((wv + 8) << 4) + lrow];
                float v2 = sbias[OBHH0 + ((wv + 16) << 4) + lrow];
                acc0 = (f32x4){v0, v0, v0, v0};
                acc1 = (f32x4){v1, v1, v1, v1};
                acc2 = (f32x4){v2, v2, v2, v2};
                ecc0 = (f32x4){0, 0, 0, 0}; ecc1 = ecc0; ecc2 = ecc0;
            }
#pragma unroll
            for (int kt = 0; kt < 4; ++kt) {
                f16x8 ah = *(const f16x8*)&bHh[lrow][kt * 32 + lk8];
                f16x8 al = *(const f16x8*)&bHl[lrow][kt * 32 + lk8];
                f16x8 bh0 = *((const f16x8*)(hh0h + (size_t)((wv) * 4 + kt) * 512) + l);
                f16x8 bl0 = *((const f16x8*)(hh0l + (size_t)((wv) * 4 + kt) * 512) + l);
                f16x8 bh1 = *((const f16x8*)(hh0h + (size_t)((wv + 8) * 4 + kt) * 512) + l);
                f16x8 bl1 = *((const f16x8*)(hh0l + (size_t)((wv + 8) * 4 + kt) * 512) + l);
                f16x8 bh2 = *((const f16x8*)(hh0h + (size_t)((wv + 16) * 4 + kt) * 512) + l);
                f16x8 bl2 = *((const f16x8*)(hh0l + (size_t)((wv + 16) * 4 + kt) * 512) + l);
                acc0 = MFMA(ah, bh0, acc0); ecc0 = MFMA(ah, bl0, ecc0); ecc0 = MFMA(al, bh0, ecc0);
                acc1 = MFMA(ah, bh1, acc1); ecc1 = MFMA(ah, bl1, ecc1); ecc1 = MFMA(al, bh1, ecc1);
                acc2 = MFMA(ah, bh2, acc2); ecc2 = MFMA(ah, bl2, ecc2); ecc2 = MFMA(al, bh2, ecc2);
            }
            // y = h1 @ wout + bout  (lanes 0-31: row wv ; lanes 32-63: row wv+8)
            {
                int yrow = wv + ((l >> 5) << 3);
                int ll = l & 31;
                int c0 = ll << 2;
                float4 hv = *(const float4*)&hF[yrow][c0];
                float p0 = hv.x * swout[c0 * 3] + hv.y * swout[(c0 + 1) * 3] +
                           hv.z * swout[(c0 + 2) * 3] + hv.w * swout[(c0 + 3) * 3];
                float p1 = hv.x * swout[c0 * 3 + 1] + hv.y * swout[(c0 + 1) * 3 + 1] +
                           hv.z * swout[(c0 + 2) * 3 + 1] + hv.w * swout[(c0 + 3) * 3 + 1];
                float p2 = hv.x * swout[c0 * 3 + 2] + hv.y * swout[(c0 + 1) * 3 + 2] +
                           hv.z * swout[(c0 + 2) * 3 + 2] + hv.w * swout[(c0 + 3) * 3 + 2];
#pragma unroll
                for (int m = 16; m >= 1; m >>= 1) {
                    p0 += __shfl_xor(p0, m, 64);
                    p1 += __shfl_xor(p1, m, 64);
                    p2 += __shfl_xor(p2, m, 64);
                }
                if (ll == 0) {
                    int idx = sIdx[yrow] + s * 34;
                    out[idx * 3 + 0] = p0 + sbout[0];
                    out[idx * 3 + 1] = p1 + sbout[1];
                    out[idx * 3 + 2] = p2 + sbout[2];
                }
            }
            // GRU0 combine: h2 -> bufB cols 0..127
            {
                int col = (wv << 4) + lrow;
                float wxr0 = swi0[col], wxr1 = swi0[384 + col];
                float wxz0 = swi0[128 + col], wxz1 = swi0[384 + 128 + col];
                float wxn0 = swi0[256 + col], wxn1 = swi0[384 + 256 + col];
                float bir = sbias[OBIH0 + col], biz = sbias[OBIH0 + 128 + col], bin = sbias[OBIH0 + 256 + col];
#pragma unroll
                for (int r = 0; r < 4; ++r) {
                    int row = rbase + r;
                    float ghr = acc0[r] + ecc0[r] * INV;
                    float ghz = acc1[r] + ecc1[r] * INV;
                    float ghn = acc2[r] + ecc2[r] * INV;
                    float xa = sx0[row], xb = sx1[row];
                    float rg = fast_sigmoid(bir + xa * wxr0 + xb * wxr1 + ghr);
                    float zg = fast_sigmoid(biz + xa * wxz0 + xb * wxz1 + ghz);
                    float nn = fast_tanh(bin + xa * wxn0 + xb * wxn1 + rg * ghn);
                    float h1 = hF[row][col];
                    float h2 = (1.0f - zg) * nn + zg * h1;
                    _Float16 hh = (_Float16)h2;
                    bBh[row][col] = hh;
                    bBl[row][col] = (_Float16)((h2 - (float)hh) * LS);
                }
            }
        }
        __syncthreads();

        // P7: gi1 = h2 @ wih1 + bih1 ; gh1 = h1 @ whh1 + bhh1 ; GRU1 combine -> hF
        {
            f32x4 aI0, aI1, aI2, eI0, eI1, eI2;
            {
                float v0 = sbias[OBIH1 + ((wv) << 4) + lrow];
                float v1 = sbias[OBIH1 + ((wv + 8) << 4) + lrow];
                float v2 = sbias[OBIH1 + ((wv + 16) << 4) + lrow];
                aI0 = (f32x4){v0, v0, v0, v0};
                aI1 = (f32x4){v1, v1, v1, v1};
                aI2 = (f32x4){v2, v2, v2, v2};
                eI0 = (f32x4){0, 0, 0, 0}; eI1 = eI0; eI2 = eI0;
            }
#pragma unroll
            for (int kt = 0; kt < 4; ++kt) {
                f16x8 ah = *(const f16x8*)&bBh[lrow][kt * 32 + lk8];
                f16x8 al = *(const f16x8*)&bBl[lrow][kt * 32 + lk8];
                f16x8 bh0 = *((const f16x8*)(ih1h + (size_t)((wv) * 4 + kt) * 512) + l);
                f16x8 bl0 = *((const f16x8*)(ih1l + (size_t)((wv) * 4 + kt) * 512) + l);
                f16x8 bh1 = *((const f16x8*)(ih1h + (size_t)((wv + 8) * 4 + kt) * 512) + l);
                f16x8 bl1 = *((const f16x8*)(ih1l + (size_t)((wv + 8) * 4 + kt) * 512) + l);
                f16x8 bh2 = *((const f16x8*)(ih1h + (size_t)((wv + 16) * 4 + kt) * 512) + l);
                f16x8 bl2 = *((const f16x8*)(ih1l + (size_t)((wv + 16) * 4 + kt) * 512) + l);
                aI0 = MFMA(ah, bh0, aI0); eI0 = MFMA(ah, bl0, eI0); eI0 = MFMA(al, bh0, eI0);
                aI1 = MFMA(ah, bh1, aI1); eI1 = MFMA(ah, bl1, eI1); eI1 = MFMA(al, bh1, eI1);
                aI2 = MFMA(ah, bh2, aI2); eI2 = MFMA(ah, bl2, eI2); eI2 = MFMA(al, bh2, eI2);
            }
            f32x4 gi0 = aI0 + eI0 * INV;
            f32x4 gi1 = aI1 + eI1 * INV;
            f32x4 gi2 = aI2 + eI2 * INV;

            f32x4 aH0, aH1, aH2, eH0, eH1, eH2;
            {
                float v0 = sbias[OBHH1 + ((wv) << 4) + lrow];
                float v1 = sbias[OBHH1 + ((wv + 8) << 4) + lrow];
                float v2 = sbias[OBHH1 + ((wv + 16) << 4) + lrow];
                aH0 = (f32x4){v0, v0, v0, v0};
                aH1 = (f32x4){v1, v1, v1, v1};
                aH2 = (f32x4){v2, v2, v2, v2};
                eH0 = (f32x4){0, 0, 0, 0}; eH1 = eH0; eH2 = eH0;
            }
#pragma unroll
            for (int kt = 0; kt < 4; ++kt) {
                f16x8 ah = *(const f16x8*)&bHh[lrow][kt * 32 + lk8];
                f16x8 al = *(const f16x8*)&bHl[lrow][kt * 32 + lk8];
                f16x8 bh0 = *((const f16x8*)(hh1h + (size_t)((wv) * 4 + kt) * 512) + l);
                f16x8 bl0 = *((const f16x8*)(hh1l + (size_t)((wv) * 4 + kt) * 512) + l);
                f16x8 bh1 = *((const f16x8*)(hh1h + (size_t)((wv + 8) * 4 + kt) * 512) + l);
                f16x8 bl1 = *((const f16x8*)(hh1l + (size_t)((wv + 8) * 4 + kt) * 512) + l);
                f16x8 bh2 = *((const f16x8*)(hh1h + (size_t)((wv + 16) * 4 + kt) * 512) + l);
                f16x8 bl2 = *((const f16x8*)(hh1l + (size_t)((wv + 16) * 4 + kt) * 512) + l);
                aH0 = MFMA(ah, bh0, aH0); eH0 = MFMA(ah, bl0, eH0); eH0 = MFMA(al, bh0, eH0);
                aH1 = MFMA(ah, bh1, aH1); eH1 = MFMA(ah, bl1, eH1); eH1 = MFMA(al, bh1, eH1);
                aH2 = MFMA(ah, bh2, aH2); eH2 = MFMA(ah, bl2, eH2); eH2 = MFMA(al, bh2, eH2);
            }
#pragma unroll
            for (int r = 0; r < 4; ++r) {
                int row = rbase + r, col = (wv << 4) + lrow;
                float ghr = aH0[r] + eH0[r] * INV;
                float ghz = aH1[r] + eH1[r] * INV;
                float ghn = aH2[r] + eH2[r] * INV;
                float rg = fast_sigmoid(gi0[r] + ghr);
                float zg = fast_sigmoid(gi1[r] + ghz);
                float nn = fast_tanh(gi2[r] + rg * ghn);
                float h1 = hF[row][col];
                float h2 = (1.0f - zg) * nn + zg * h1;
                hF[row][col] = (smm[row] != 0.0f) ? h2 : h1;
            }
        }
        __syncthreads();
    }
}

extern "C" void kernel_launch(void* const* d_in, const int* in_sizes, int n_in,
                              void* d_out, int out_size, void* d_ws, size_t ws_size,
                              hipStream_t stream) {
    const float* x2d  = (const float*)d_in[0];
    const int*   mask = (const int*)d_in[1];
    const float* w0   = (const float*)d_in[2];
    const float* b0   = (const float*)d_in[3];
    const float* w1   = (const float*)d_in[4];
    const float* b1   = (const float*)d_in[5];
    const float* w2   = (const float*)d_in[6];
    const float* b2   = (const float*)d_in[7];
    const float* wih0 = (const float*)d_in[8];
    const float* whh0 = (const float*)d_in[9];
    const float* bih0 = (const float*)d_in[10];
    const float* bhh0 = (const float*)d_in[11];
    const float* wih1 = (const float*)d_in[12];
    const float* whh1 = (const float*)d_in[13];
    const float* bih1 = (const float*)d_in[14];
    const float* bhh1 = (const float*)d_in[15];
    const float* wout = (const float*)d_in[16];
    const float* bout = (const float*)d_in[17];
    const float* h0   = (const float*)d_in[18];
    float* out = (float*)d_out;

    _Float16* base = (_Float16*)d_ws;
    _Float16* pw0h  = base;                 // 32768
    _Float16* pw1h  = base + 32768;         // 65536
    _Float16* pw2h  = base + 98304;         // 32768
    _Float16* ph0h  = base + 131072;        // 49152 (whh0)
    _Float16* pi1h  = base + 180224;        // 49152 (wih1)
    _Float16* ph1h  = base + 229376;        // 49152 (whh1)
    _Float16* lobase = base + 278528;
    _Float16* pw0l  = lobase;
    _Float16* pw1l  = lobase + 32768;
    _Float16* pw2l  = lobase + 98304;
    _Float16* ph0l  = lobase + 131072;
    _Float16* pi1l  = lobase + 180224;
    _Float16* ph1l  = lobase + 229376;

    hipLaunchKernelGGL(prep_hl, dim3(128), dim3(256), 0, stream, w0,   pw0h, pw0l, 128, 256);
    hipLaunchKernelGGL(prep_hl, dim3(256), dim3(256), 0, stream, w1,   pw1h, pw1l, 256, 256);
    hipLaunchKernelGGL(prep_hl, dim3(128), dim3(256), 0, stream, w2,   pw2h, pw2l, 256, 128);
    hipLaunchKernelGGL(prep_hl, dim3(192), dim3(256), 0, stream, whh0, ph0h, ph0l, 128, 384);
    hipLaunchKernelGGL(prep_hl, dim3(192), dim3(256), 0, stream, wih1, pi1h, pi1l, 128, 384);
    hipLaunchKernelGGL(prep_hl, dim3(192), dim3(256), 0, stream, whh1, ph1h, ph1l, 128, 384);

    hipLaunchKernelGGL(odernn_mfma, dim3(68), dim3(512), 0, stream,
        x2d, mask, pw0h, pw0l, pw1h, pw1l, pw2h, pw2l,
        ph0h, ph0l, pi1h, pi1l, ph1h, ph1l,
        b0, b1, b2, bhh0, bih0, wih0, bih1, bhh1, wout, bout, h0, out);
}

// Round 4
// 6755.146 us; speedup vs baseline: 5.5120x; 1.0209x over previous
//
#include <hip/hip_runtime.h>

typedef _Float16 f16x8 __attribute__((ext_vector_type(8)));
typedef float f32x4 __attribute__((ext_vector_type(4)));

constexpr int S_ = 128;
constexpr float DT_ = 0.1f;
constexpr float LS = 2048.0f;          // lo-term scale (2^11) keeps fp16 lo parts normal
constexpr float INV = 1.0f / 2048.0f;

#define MFMA(a, b, c) __builtin_amdgcn_mfma_f32_16x16x32_f16((a), (b), (c), 0, 0, 0)

// bias LDS offsets (floats)
#define OB0   0
#define OB1   256
#define OB2   512
#define OBHH0 640
#define OBIH0 1024
#define OBIH1 1408
#define OBHH1 1792
#define NBIAS 2176

__device__ __forceinline__ float fast_tanh(float x) {
    float e = __expf(2.0f * x);
    return 1.0f - 2.0f / (e + 1.0f);
}
__device__ __forceinline__ float fast_sigmoid(float x) {
    return 1.0f / (1.0f + __expf(-x));
}

// fp32 row-major KxN -> fp16 hi/lo MFMA-B-fragment blobs.
// Tile (nt,kt) at ((nt*KT)+kt)*512; elem lane*8+j <-> B[kt*32+(lane>>4)*8+j][nt*16+(lane&15)].
__global__ void prep_hl(const float* __restrict__ src, _Float16* __restrict__ hi,
                        _Float16* __restrict__ lo, int K, int N) {
    int e = blockIdx.x * 256 + threadIdx.x;
    if (e >= K * N) return;
    int tile = e >> 9, r = e & 511;
    int lane = r >> 3, j = r & 7;
    int KT = K >> 5;
    int nt = tile / KT, kt = tile - nt * KT;
    int k = kt * 32 + ((lane >> 4) << 3) + j;
    int n = nt * 16 + (lane & 15);
    float v = src[k * N + n];
    _Float16 h = (_Float16)v;
    hi[e] = h;
    lo[e] = (_Float16)((v - (float)h) * LS);
}

__global__ __launch_bounds__(512, 2) void odernn_mfma(
    const float* __restrict__ x2d, const int* __restrict__ maskp,
    const _Float16* __restrict__ w0h, const _Float16* __restrict__ w0l,
    const _Float16* __restrict__ w1hg, const _Float16* __restrict__ w1lg,
    const _Float16* __restrict__ w2h, const _Float16* __restrict__ w2l,
    const _Float16* __restrict__ hh0h, const _Float16* __restrict__ hh0l,
    const _Float16* __restrict__ ih1h, const _Float16* __restrict__ ih1l,
    const _Float16* __restrict__ hh1h, const _Float16* __restrict__ hh1l,
    const float* __restrict__ b0, const float* __restrict__ b1,
    const float* __restrict__ b2, const float* __restrict__ bhh0,
    const float* __restrict__ bih0, const float* __restrict__ wih0,
    const float* __restrict__ bih1, const float* __restrict__ bhh1,
    const float* __restrict__ wout, const float* __restrict__ bout,
    const float* __restrict__ h0, float* __restrict__ out)
{
    __shared__ float hF[16][128];                       // fp32 master hidden state
    __shared__ _Float16 bAh[16][264], bAl[16][264];     // t2 (256-wide) hi/lo
    __shared__ _Float16 bBh[16][264], bBl[16][264];     // t1 / h2 hi/lo
    __shared__ _Float16 bHh[16][136], bHl[16][136];     // current h / h1 hi/lo
    __shared__ float sbias[NBIAS];
    __shared__ float swi0[768];
    __shared__ float swout[384];
    __shared__ float sbout[4];
    __shared__ float sx0[16], sx1[16], smm[16];
    __shared__ int sIdx[16];

    const int tid = (int)threadIdx.x;
    const int wv = tid >> 6;            // wave 0..7
    const int l = tid & 63;
    const int lrow = l & 15;            // A-row / D-col within tile
    const int lk8 = (l >> 4) << 3;      // k-octet within 32-wide k-tile
    const int rbase = (l >> 4) << 2;    // D-row base for this lane

    // ---- LDS init ----
    for (int e = tid; e < 256; e += 512) { sbias[OB0 + e] = b0[e]; sbias[OB1 + e] = b1[e]; }
    for (int e = tid; e < 128; e += 512) sbias[OB2 + e] = b2[e];
    for (int e = tid; e < 384; e += 512) {
        sbias[OBHH0 + e] = bhh0[e];
        sbias[OBIH0 + e] = bih0[e];
        sbias[OBIH1 + e] = bih1[e];
        sbias[OBHH1 + e] = bhh1[e];
        swout[e] = wout[e];
    }
    for (int e = tid; e < 768; e += 512) swi0[e] = wih0[e];
    if (tid < 3) sbout[tid] = bout[tid];
    for (int e = tid; e < 2048; e += 512) {
        int row = e >> 7, col = e & 127;
        float v = h0[col];
        hF[row][col] = v;
        _Float16 hh = (_Float16)v;
        bHh[row][col] = hh;
        bHl[row][col] = (_Float16)((v - (float)hh) * LS);
    }
    if (tid < 16) {
        int grow = (int)blockIdx.x * 16 + tid;
        int bb = grow / 34, nn = grow - bb * 34;
        sIdx[tid] = bb * (S_ * 34) + nn;
    }
    __syncthreads();

    for (int s = 0; s < S_; ++s) {
        // x/mask for this step (consumed at P5, several barriers later)
        if (tid < 16) {
            int idx = sIdx[tid] + s * 34;
            float fm = (float)maskp[idx];
            smm[tid] = fm;
            sx0[tid] = x2d[2 * idx] * fm;
            sx1[tid] = x2d[2 * idx + 1] * fm;
        }

        // ================= 4 Euler steps =================
        for (int it = 0; it < 4; ++it) {
            // P1: t1 = tanh(h @ w0 + b0) -> bufB   (K=128 KT=4, NT=16: 2/wave)
            {
                const int n0 = wv << 4, n1 = (wv + 8) << 4;
                float bv0 = sbias[OB0 + n0 + lrow], bv1 = sbias[OB0 + n1 + lrow];
                f32x4 a0 = {bv0, bv0, bv0, bv0}, a1 = {bv1, bv1, bv1, bv1};
                f32x4 e0 = {0, 0, 0, 0}, e1 = {0, 0, 0, 0};
                const f16x8* B0h = (const f16x8*)(w0h + (size_t)(wv * 4) * 512) + l;
                const f16x8* B0l = (const f16x8*)(w0l + (size_t)(wv * 4) * 512) + l;
                const f16x8* B1h = (const f16x8*)(w0h + (size_t)((wv + 8) * 4) * 512) + l;
                const f16x8* B1l = (const f16x8*)(w0l + (size_t)((wv + 8) * 4) * 512) + l;
#pragma unroll
                for (int kt = 0; kt < 4; ++kt) {
                    f16x8 ah = *(const f16x8*)&bHh[lrow][kt * 32 + lk8];
                    f16x8 al = *(const f16x8*)&bHl[lrow][kt * 32 + lk8];
                    f16x8 bh0 = B0h[kt * 64], bl0 = B0l[kt * 64];
                    f16x8 bh1 = B1h[kt * 64], bl1 = B1l[kt * 64];
                    a0 = MFMA(ah, bh0, a0);
                    e0 = MFMA(ah, bl0, e0);
                    e0 = MFMA(al, bh0, e0);
                    a1 = MFMA(ah, bh1, a1);
                    e1 = MFMA(ah, bl1, e1);
                    e1 = MFMA(al, bh1, e1);
                }
#pragma unroll
                for (int r = 0; r < 4; ++r) {
                    int row = rbase + r;
                    float v0 = fast_tanh(a0[r] + e0[r] * INV);
                    float v1 = fast_tanh(a1[r] + e1[r] * INV);
                    _Float16 hh = (_Float16)v0;
                    bBh[row][n0 + lrow] = hh;
                    bBl[row][n0 + lrow] = (_Float16)((v0 - (float)hh) * LS);
                    hh = (_Float16)v1;
                    bBh[row][n1 + lrow] = hh;
                    bBl[row][n1 + lrow] = (_Float16)((v1 - (float)hh) * LS);
                }
            }
            __syncthreads();

            // P2: t2 = tanh(t1 @ w1 + b1) -> bufA  (K=256 KT=8, NT=16: 2/wave)
            {
                const int n0 = wv << 4, n1 = (wv + 8) << 4;
                float bv0 = sbias[OB1 + n0 + lrow], bv1 = sbias[OB1 + n1 + lrow];
                f32x4 a0 = {bv0, bv0, bv0, bv0}, a1 = {bv1, bv1, bv1, bv1};
                f32x4 e0 = {0, 0, 0, 0}, e1 = {0, 0, 0, 0};
                const f16x8* B0h = (const f16x8*)(w1hg + (size_t)(wv * 8) * 512) + l;
                const f16x8* B0l = (const f16x8*)(w1lg + (size_t)(wv * 8) * 512) + l;
                const f16x8* B1h = (const f16x8*)(w1hg + (size_t)((wv + 8) * 8) * 512) + l;
                const f16x8* B1l = (const f16x8*)(w1lg + (size_t)((wv + 8) * 8) * 512) + l;
#pragma unroll
                for (int kt = 0; kt < 8; ++kt) {
                    f16x8 ah = *(const f16x8*)&bBh[lrow][kt * 32 + lk8];
                    f16x8 al = *(const f16x8*)&bBl[lrow][kt * 32 + lk8];
                    f16x8 bh0 = B0h[kt * 64], bl0 = B0l[kt * 64];
                    f16x8 bh1 = B1h[kt * 64], bl1 = B1l[kt * 64];
                    a0 = MFMA(ah, bh0, a0);
                    e0 = MFMA(ah, bl0, e0);
                    e0 = MFMA(al, bh0, e0);
                    a1 = MFMA(ah, bh1, a1);
                    e1 = MFMA(ah, bl1, e1);
                    e1 = MFMA(al, bh1, e1);
                }
#pragma unroll
                for (int r = 0; r < 4; ++r) {
                    int row = rbase + r;
                    float v0 = fast_tanh(a0[r] + e0[r] * INV);
                    float v1 = fast_tanh(a1[r] + e1[r] * INV);
                    _Float16 hh = (_Float16)v0;
                    bAh[row][n0 + lrow] = hh;
                    bAl[row][n0 + lrow] = (_Float16)((v0 - (float)hh) * LS);
                    hh = (_Float16)v1;
                    bAh[row][n1 + lrow] = hh;
                    bAl[row][n1 + lrow] = (_Float16)((v1 - (float)hh) * LS);
                }
            }
            __syncthreads();

            // P3: f = t2 @ w2 + b2 ; hF += DT*f ; cast new h -> bufH  (K=256 KT=8, NT=8)
            {
                const int n0 = wv << 4;
                float bv = sbias[OB2 + n0 + lrow];
                f32x4 acc = {bv, bv, bv, bv};
                f32x4 ecc = {0, 0, 0, 0};
                const f16x8* Bh = (const f16x8*)(w2h + (size_t)(wv * 8) * 512) + l;
                const f16x8* Bl = (const f16x8*)(w2l + (size_t)(wv * 8) * 512) + l;
#pragma unroll
                for (int kt = 0; kt < 8; ++kt) {
                    f16x8 ah = *(const f16x8*)&bAh[lrow][kt * 32 + lk8];
                    f16x8 al = *(const f16x8*)&bAl[lrow][kt * 32 + lk8];
                    f16x8 bh = Bh[kt * 64], bl = Bl[kt * 64];
                    acc = MFMA(ah, bh, acc);
                    ecc = MFMA(ah, bl, ecc);
                    ecc = MFMA(al, bh, ecc);
                }
#pragma unroll
                for (int r = 0; r < 4; ++r) {
                    int row = rbase + r, col = n0 + lrow;
                    float v = hF[row][col] + DT_ * (acc[r] + ecc[r] * INV);
                    hF[row][col] = v;
                    _Float16 hh = (_Float16)v;
                    bHh[row][col] = hh;
                    bHl[row][col] = (_Float16)((v - (float)hh) * LS);
                }
            }
            __syncthreads();
        }

        // P5: gh0 = h1 @ whh0 + bhh0 (KT=4, NT=24: 3/wave) ; y-out ; GRU0 combine -> bufB
        {
            f32x4 acc0, acc1, acc2, ecc0, ecc1, ecc2;
            {
                float v0 = sbias[OBHH0 + ((wv) << 4) + lrow];
                float v1 = sbias[OBHH0 + ((wv + 8) << 4) + lrow];
                float v2 = sbias[OBHH0 + ((wv + 16) << 4) + lrow];
                acc0 = (f32x4){v0, v0, v0, v0};
                acc1 = (f32x4){v1, v1, v1, v1};
                acc2 = (f32x4){v2, v2, v2, v2};
                ecc0 = (f32x4){0, 0, 0, 0}; ecc1 = ecc0; ecc2 = ecc0;
            }
#pragma unroll
            for (int kt = 0; kt < 4; ++kt) {
                f16x8 ah = *(const f16x8*)&bHh[lrow][kt * 32 + lk8];
                f16x8 al = *(const f16x8*)&bHl[lrow][kt * 32 + lk8];
                f16x8 bh0 = *((const f16x8*)(hh0h + (size_t)((wv) * 4 + kt) * 512) + l);
                f16x8 bl0 = *((const f16x8*)(hh0l + (size_t)((wv) * 4 + kt) * 512) + l);
                f16x8 bh1 = *((const f16x8*)(hh0h + (size_t)((wv + 8) * 4 + kt) * 512) + l);
                f16x8 bl1 = *((const f16x8*)(hh0l + (size_t)((wv + 8) * 4 + kt) * 512) + l);
                f16x8 bh2 = *((const f16x8*)(hh0h + (size_t)((wv + 16) * 4 + kt) * 512) + l);
                f16x8 bl2 = *((const f16x8*)(hh0l + (size_t)((wv + 16) * 4 + kt) * 512) + l);
                acc0 = MFMA(ah, bh0, acc0); ecc0 = MFMA(ah, bl0, ecc0); ecc0 = MFMA(al, bh0, ecc0);
                acc1 = MFMA(ah, bh1, acc1); ecc1 = MFMA(ah, bl1, ecc1); ecc1 = MFMA(al, bh1, ecc1);
                acc2 = MFMA(ah, bh2, acc2); ecc2 = MFMA(ah, bl2, ecc2); ecc2 = MFMA(al, bh2, ecc2);
            }
            // y = h1 @ wout + bout  (lanes 0-31: row wv ; lanes 32-63: row wv+8)
            {
                int yrow = wv + ((l >> 5) << 3);
                int ll = l & 31;
                int c0 = ll << 2;
                float4 hv = *(const float4*)&hF[yrow][c0];
                float p0 = hv.x * swout[c0 * 3] + hv.y * swout[(c0 + 1) * 3] +
                           hv.z * swout[(c0 + 2) * 3] + hv.w * swout[(c0 + 3) * 3];
                float p1 = hv.x * swout[c0 * 3 + 1] + hv.y * swout[(c0 + 1) * 3 + 1] +
                           hv.z * swout[(c0 + 2) * 3 + 1] + hv.w * swout[(c0 + 3) * 3 + 1];
                float p2 = hv.x * swout[c0 * 3 + 2] + hv.y * swout[(c0 + 1) * 3 + 2] +
                           hv.z * swout[(c0 + 2) * 3 + 2] + hv.w * swout[(c0 + 3) * 3 + 2];
#pragma unroll
                for (int m = 16; m >= 1; m >>= 1) {
                    p0 += __shfl_xor(p0, m, 64);
                    p1 += __shfl_xor(p1, m, 64);
                    p2 += __shfl_xor(p2, m, 64);
                }
                if (ll == 0) {
                    int idx = sIdx[yrow] + s * 34;
                    out[idx * 3 + 0] = p0 + sbout[0];
                    out[idx * 3 + 1] = p1 + sbout[1];
                    out[idx * 3 + 2] = p2 + sbout[2];
                }
            }
            // GRU0 combine: h2 -> bufB cols 0..127
            {
                int col = (wv << 4) + lrow;
                float wxr0 = swi0[col], wxr1 = swi0[384 + col];
                float wxz0 = swi0[128 + col], wxz1 = swi0[384 + 128 + col];
                float wxn0 = swi0[256 + col], wxn1 = swi0[384 + 256 + col];
                float bir = sbias[OBIH0 + col], biz = sbias[OBIH0 + 128 + col], bin = sbias[OBIH0 + 256 + col];
#pragma unroll
                for (int r = 0; r < 4; ++r) {
                    int row = rbase + r;
                    float ghr = acc0[r] + ecc0[r] * INV;
                    float ghz = acc1[r] + ecc1[r] * INV;
                    float ghn = acc2[r] + ecc2[r] * INV;
                    float xa = sx0[row], xb = sx1[row];
                    float rg = fast_sigmoid(bir + xa * wxr0 + xb * wxr1 + ghr);
                    float zg = fast_sigmoid(biz + xa * wxz0 + xb * wxz1 + ghz);
                    float nn = fast_tanh(bin + xa * wxn0 + xb * wxn1 + rg * ghn);
                    float h1 = hF[row][col];
                    float h2 = (1.0f - zg) * nn + zg * h1;
                    _Float16 hh = (_Float16)h2;
                    bBh[row][col] = hh;
                    bBl[row][col] = (_Float16)((h2 - (float)hh) * LS);
                }
            }
        }
        __syncthreads();

        // P7: gi1 = h2 @ wih1 + bih1 ; gh1 = h1 @ whh1 + bhh1 ; GRU1 combine -> hF + bufH
        {
            f32x4 aI0, aI1, aI2, eI0, eI1, eI2;
            {
                float v0 = sbias[OBIH1 + ((wv) << 4) + lrow];
                float v1 = sbias[OBIH1 + ((wv + 8) << 4) + lrow];
                float v2 = sbias[OBIH1 + ((wv + 16) << 4) + lrow];
                aI0 = (f32x4){v0, v0, v0, v0};
                aI1 = (f32x4){v1, v1, v1, v1};
                aI2 = (f32x4){v2, v2, v2, v2};
                eI0 = (f32x4){0, 0, 0, 0}; eI1 = eI0; eI2 = eI0;
            }
#pragma unroll
            for (int kt = 0; kt < 4; ++kt) {
                f16x8 ah = *(const f16x8*)&bBh[lrow][kt * 32 + lk8];
                f16x8 al = *(const f16x8*)&bBl[lrow][kt * 32 + lk8];
                f16x8 bh0 = *((const f16x8*)(ih1h + (size_t)((wv) * 4 + kt) * 512) + l);
                f16x8 bl0 = *((const f16x8*)(ih1l + (size_t)((wv) * 4 + kt) * 512) + l);
                f16x8 bh1 = *((const f16x8*)(ih1h + (size_t)((wv + 8) * 4 + kt) * 512) + l);
                f16x8 bl1 = *((const f16x8*)(ih1l + (size_t)((wv + 8) * 4 + kt) * 512) + l);
                f16x8 bh2 = *((const f16x8*)(ih1h + (size_t)((wv + 16) * 4 + kt) * 512) + l);
                f16x8 bl2 = *((const f16x8*)(ih1l + (size_t)((wv + 16) * 4 + kt) * 512) + l);
                aI0 = MFMA(ah, bh0, aI0); eI0 = MFMA(ah, bl0, eI0); eI0 = MFMA(al, bh0, eI0);
                aI1 = MFMA(ah, bh1, aI1); eI1 = MFMA(ah, bl1, eI1); eI1 = MFMA(al, bh1, eI1);
                aI2 = MFMA(ah, bh2, aI2); eI2 = MFMA(ah, bl2, eI2); eI2 = MFMA(al, bh2, eI2);
            }
            f32x4 gi0 = aI0 + eI0 * INV;
            f32x4 gi1 = aI1 + eI1 * INV;
            f32x4 gi2 = aI2 + eI2 * INV;

            f32x4 aH0, aH1, aH2, eH0, eH1, eH2;
            {
                float v0 = sbias[OBHH1 + ((wv) << 4) + lrow];
                float v1 = sbias[OBHH1 + ((wv + 8) << 4) + lrow];
                float v2 = sbias[OBHH1 + ((wv + 16) << 4) + lrow];
                aH0 = (f32x4){v0, v0, v0, v0};
                aH1 = (f32x4){v1, v1, v1, v1};
                aH2 = (f32x4){v2, v2, v2, v2};
                eH0 = (f32x4){0, 0, 0, 0}; eH1 = eH0; eH2 = eH0;
            }
#pragma unroll
            for (int kt = 0; kt < 4; ++kt) {
                f16x8 ah = *(const f16x8*)&bHh[lrow][kt * 32 + lk8];
                f16x8 al = *(const f16x8*)&bHl[lrow][kt * 32 + lk8];
                f16x8 bh0 = *((const f16x8*)(hh1h + (size_t)((wv) * 4 + kt) * 512) + l);
                f16x8 bl0 = *((const f16x8*)(hh1l + (size_t)((wv) * 4 + kt) * 512) + l);
                f16x8 bh1 = *((const f16x8*)(hh1h + (size_t)((wv + 8) * 4 + kt) * 512) + l);
                f16x8 bl1 = *((const f16x8*)(hh1l + (size_t)((wv + 8) * 4 + kt) * 512) + l);
                f16x8 bh2 = *((const f16x8*)(hh1h + (size_t)((wv + 16) * 4 + kt) * 512) + l);
                f16x8 bl2 = *((const f16x8*)(hh1l + (size_t)((wv + 16) * 4 + kt) * 512) + l);
                aH0 = MFMA(ah, bh0, aH0); eH0 = MFMA(ah, bl0, eH0); eH0 = MFMA(al, bh0, eH0);
                aH1 = MFMA(ah, bh1, aH1); eH1 = MFMA(ah, bl1, eH1); eH1 = MFMA(al, bh1, eH1);
                aH2 = MFMA(ah, bh2, aH2); eH2 = MFMA(ah, bl2, eH2); eH2 = MFMA(al, bh2, eH2);
            }
            __syncthreads();   // all reads of bHh/bHl for this step are done
#pragma unroll
            for (int r = 0; r < 4; ++r) {
                int row = rbase + r, col = (wv << 4) + lrow;
                float ghr = aH0[r] + eH0[r] * INV;
                float ghz = aH1[r] + eH1[r] * INV;
                float ghn = aH2[r] + eH2[r] * INV;
                float rg = fast_sigmoid(gi0[r] + ghr);
                float zg = fast_sigmoid(gi1[r] + ghz);
                float nn = fast_tanh(gi2[r] + rg * ghn);
                float h1 = hF[row][col];
                float h2 = (1.0f - zg) * nn + zg * h1;
                float v = (smm[row] != 0.0f) ? h2 : h1;
                hF[row][col] = v;
                _Float16 hh = (_Float16)v;
                bHh[row][col] = hh;
                bHl[row][col] = (_Float16)((v - (float)hh) * LS);
            }
        }
        __syncthreads();
    }
}

extern "C" void kernel_launch(void* const* d_in, const int* in_sizes, int n_in,
                              void* d_out, int out_size, void* d_ws, size_t ws_size,
                              hipStream_t stream) {
    const float* x2d  = (const float*)d_in[0];
    const int*   mask = (const int*)d_in[1];
    const float* w0   = (const float*)d_in[2];
    const float* b0   = (const float*)d_in[3];
    const float* w1   = (const float*)d_in[4];
    const float* b1   = (const float*)d_in[5];
    const float* w2   = (const float*)d_in[6];
    const float* b2   = (const float*)d_in[7];
    const float* wih0 = (const float*)d_in[8];
    const float* whh0 = (const float*)d_in[9];
    const float* bih0 = (const float*)d_in[10];
    const float* bhh0 = (const float*)d_in[11];
    const float* wih1 = (const float*)d_in[12];
    const float* whh1 = (const float*)d_in[13];
    const float* bih1 = (const float*)d_in[14];
    const float* bhh1 = (const float*)d_in[15];
    const float* wout = (const float*)d_in[16];
    const float* bout = (const float*)d_in[17];
    const float* h0   = (const float*)d_in[18];
    float* out = (float*)d_out;

    _Float16* base = (_Float16*)d_ws;
    _Float16* pw0h  = base;                 // 32768
    _Float16* pw1h  = base + 32768;         // 65536
    _Float16* pw2h  = base + 98304;         // 32768
    _Float16* ph0h  = base + 131072;        // 49152 (whh0)
    _Float16* pi1h  = base + 180224;        // 49152 (wih1)
    _Float16* ph1h  = base + 229376;        // 49152 (whh1)
    _Float16* lobase = base + 278528;
    _Float16* pw0l  = lobase;
    _Float16* pw1l  = lobase + 32768;
    _Float16* pw2l  = lobase + 98304;
    _Float16* ph0l  = lobase + 131072;
    _Float16* pi1l  = lobase + 180224;
    _Float16* ph1l  = lobase + 229376;

    hipLaunchKernelGGL(prep_hl, dim3(128), dim3(256), 0, stream, w0,   pw0h, pw0l, 128, 256);
    hipLaunchKernelGGL(prep_hl, dim3(256), dim3(256), 0, stream, w1,   pw1h, pw1l, 256, 256);
    hipLaunchKernelGGL(prep_hl, dim3(128), dim3(256), 0, stream, w2,   pw2h, pw2l, 256, 128);
    hipLaunchKernelGGL(prep_hl, dim3(192), dim3(256), 0, stream, whh0, ph0h, ph0l, 128, 384);
    hipLaunchKernelGGL(prep_hl, dim3(192), dim3(256), 0, stream, wih1, pi1h, pi1l, 128, 384);
    hipLaunchKernelGGL(prep_hl, dim3(192), dim3(256), 0, stream, whh1, ph1h, ph1l, 128, 384);

    hipLaunchKernelGGL(odernn_mfma, dim3(68), dim3(512), 0, stream,
        x2d, mask, pw0h, pw0l, pw1h, pw1l, pw2h, pw2l,
        ph0h, ph0l, pi1h, pi1l, ph1h, ph1l,
        b0, b1, b2, bhh0, bih0, wih0, bih1, bhh1, wout, bout, h0, out);
}